// Round 10
// baseline (468.622 us; speedup 1.0000x reference)
//
#include <hip/hip_runtime.h>

#define NN 20000      // nodes
#define NE 640000     // edges (without self loops)
#define NEE 660000    // edges + self loops
#define NP 200000     // drug pairs
#define NEG 0.2f      // leaky relu slope

// ---------------- CSR build ----------------
__global__ void k_hist(const int* __restrict__ ei, int* __restrict__ cnt) {
  int i = blockIdx.x * 256 + threadIdx.x;
  if (i >= NEE) return;
  int d = (i < NE) ? ei[NE + i] : (i - NE);
  atomicAdd(&cnt[d], 1);
}

__global__ __launch_bounds__(1024) void k_scan(const int* __restrict__ cnt, int* __restrict__ rp) {
  __shared__ int ps[1024];
  const int CH = 20;  // 1024*20 = 20480 >= 20000
  int t = threadIdx.x;
  int lo = t * CH, hi = lo + CH;
  if (hi > NN) hi = NN;
  if (lo > NN) lo = NN;
  int s = 0;
  for (int i = lo; i < hi; ++i) s += cnt[i];
  ps[t] = s;
  __syncthreads();
  for (int off = 1; off < 1024; off <<= 1) {
    int v = (t >= off) ? ps[t - off] : 0;
    __syncthreads();
    ps[t] += v;
    __syncthreads();
  }
  int run = (t > 0) ? ps[t - 1] : 0;
  for (int i = lo; i < hi; ++i) { rp[i] = run; run += cnt[i]; }
  if (t == 1023) rp[NN] = ps[1023];
}

__global__ void k_scatter(const int* __restrict__ ei, const int* __restrict__ rp,
                          int* __restrict__ cur, int* __restrict__ col) {
  int i = blockIdx.x * 256 + threadIdx.x;
  if (i >= NEE) return;
  int s, d;
  if (i < NE) { s = ei[i]; d = ei[NE + i]; } else { s = i - NE; d = s; }
  int pos = atomicAdd(&cur[d], 1);
  col[rp[d] + pos] = s;
}

// ---------------- GEMM1: h1 = x @ W1  [20000,256]x[256,256], + alphas ----------------
// h1 is stored HEAD-MAJOR: h1h[head][n][64] so each head's slice is a contiguous 5 MB.
__global__ __launch_bounds__(256) void k_gemm1(
    const float* __restrict__ x, const float* __restrict__ W1,
    const float* __restrict__ as1, const float* __restrict__ ad1,
    float* __restrict__ h1h, float* __restrict__ AS1, float* __restrict__ AD1) {
  __shared__ float xsT[256][20];  // [k][row], pad 20 keeps 16B row alignment
  int c = threadIdx.x;            // output col 0..255
  int base = blockIdx.x * 16;     // 16 rows per block
  for (int i = threadIdx.x; i < 16 * 256; i += 256) {
    int r = i >> 8, k = i & 255;
    xsT[k][r] = x[(base + r) * 256 + k];
  }
  __syncthreads();
  float acc[16];
#pragma unroll
  for (int r = 0; r < 16; ++r) acc[r] = 0.f;
#pragma unroll 2
  for (int k = 0; k < 256; ++k) {
    float wv = W1[k * 256 + c];
    const float4* xr = (const float4*)&xsT[k][0];
    float4 x0 = xr[0], x1 = xr[1], x2 = xr[2], x3 = xr[3];
    acc[0] += x0.x * wv; acc[1] += x0.y * wv; acc[2] += x0.z * wv; acc[3] += x0.w * wv;
    acc[4] += x1.x * wv; acc[5] += x1.y * wv; acc[6] += x1.z * wv; acc[7] += x1.w * wv;
    acc[8] += x2.x * wv; acc[9] += x2.y * wv; acc[10] += x2.z * wv; acc[11] += x2.w * wv;
    acc[12] += x3.x * wv; acc[13] += x3.y * wv; acc[14] += x3.z * wv; acc[15] += x3.w * wv;
  }
  int head = c >> 6, cc = c & 63;
  float asv = as1[c];  // flat [head][c&63] == c
  float adv = ad1[c];
#pragma unroll
  for (int r = 0; r < 16; ++r) {
    h1h[((size_t)head * NN + (base + r)) * 64 + cc] = acc[r];
    float vs = acc[r] * asv, vd = acc[r] * adv;
#pragma unroll
    for (int off = 32; off > 0; off >>= 1) {
      vs += __shfl_xor(vs, off);
      vd += __shfl_xor(vd, off);
    }
    if ((c & 63) == 0) {
      AS1[(base + r) * 4 + head] = vs;
      AD1[(base + r) * 4 + head] = vd;
    }
  }
}

// ---------------- GAT layer-1 aggregation, FUSED edge weights: 4 edges x 16 lanes --------
// grid = (NN/4, 4heads). Per edge the 16-lane group broadcasts AS1[s*4+head] (320 KB,
// L2-hot) and computes exp(lrelu(.)) in-register -- replaces the precomputed-w1 read
// (same load count, kills the k_edgew1 pass + 10.5 MB write + 13 MB read).
__global__ __launch_bounds__(256) void k_agg1(
    const int* __restrict__ rp, const int* __restrict__ col,
    const float* __restrict__ AS1, const float* __restrict__ AD1,
    const float* __restrict__ h1h, const float* __restrict__ b1,
    float* __restrict__ out) {
  int wave = threadIdx.x >> 6, lane = threadIdx.x & 63;
  int head = blockIdx.y;
  int n = blockIdx.x * 4 + wave;
  int g = lane >> 4, c4 = (lane & 15) * 4;
  int e0 = rp[n], e1 = rp[n + 1];
  const float* hs = h1h + (size_t)head * NN * 64;
  float adv = AD1[n * 4 + head];
  float ax = 0.f, ay = 0.f, az = 0.f, aw = 0.f, den = 0.f;
#pragma unroll 2
  for (int e = e0; e < e1; e += 4) {
    int ee = e + g;
    bool valid = ee < e1;
    int ec = valid ? ee : e1 - 1;
    int s = col[ec];
    float ev = AS1[s * 4 + head] + adv;
    ev = ev > 0.f ? ev : NEG * ev;
    float p = valid ? __expf(ev) : 0.f;
    float4 hv = *(const float4*)(hs + (size_t)s * 64 + c4);
    ax += p * hv.x; ay += p * hv.y; az += p * hv.z; aw += p * hv.w;
    den += p;
  }
  ax += __shfl_xor(ax, 16); ax += __shfl_xor(ax, 32);
  ay += __shfl_xor(ay, 16); ay += __shfl_xor(ay, 32);
  az += __shfl_xor(az, 16); az += __shfl_xor(az, 32);
  aw += __shfl_xor(aw, 16); aw += __shfl_xor(aw, 32);
  den += __shfl_xor(den, 16); den += __shfl_xor(den, 32);
  if (lane < 16) {
    float inv = 1.f / den;
    int cbase = head * 64 + c4;
    float4 bv = *(const float4*)(b1 + cbase);
    float4 o;
    o.x = ax * inv + bv.x; o.y = ay * inv + bv.y;
    o.z = az * inv + bv.z; o.w = aw * inv + bv.w;
    o.x = o.x > 0.f ? o.x : __expf(o.x) - 1.f;
    o.y = o.y > 0.f ? o.y : __expf(o.y) - 1.f;
    o.z = o.z > 0.f ? o.z : __expf(o.z) - 1.f;
    o.w = o.w > 0.f ? o.w : __expf(o.w) - 1.f;
    *(float4*)(out + (size_t)n * 256 + cbase) = o;
  }
}

// ---------------- GEMM2: h2 = h1act @ W2  [20000,256]x[256,64], + alphas ----------------
__global__ __launch_bounds__(256) void k_gemm2(
    const float* __restrict__ h1a, const float* __restrict__ W2,
    const float* __restrict__ as2, const float* __restrict__ ad2,
    float* __restrict__ h2, float* __restrict__ AS2, float* __restrict__ AD2) {
  __shared__ float xsT[256][20];
  int tid = threadIdx.x;
  int c = tid & 63, w = tid >> 6;  // wave w handles rows 4w..4w+3
  int base = blockIdx.x * 16;
  for (int i = tid; i < 16 * 256; i += 256) {
    int r = i >> 8, k = i & 255;
    xsT[k][r] = h1a[(base + r) * 256 + k];
  }
  __syncthreads();
  float acc[4] = {0.f, 0.f, 0.f, 0.f};
#pragma unroll 2
  for (int k = 0; k < 256; ++k) {
    float wv = W2[k * 64 + c];
    float4 xv = *(const float4*)&xsT[k][w * 4];
    acc[0] += xv.x * wv; acc[1] += xv.y * wv; acc[2] += xv.z * wv; acc[3] += xv.w * wv;
  }
  float asv = as2[c], adv = ad2[c];
#pragma unroll
  for (int rr = 0; rr < 4; ++rr) {
    int row = base + w * 4 + rr;
    h2[row * 64 + c] = acc[rr];
    float vs = acc[rr] * asv, vd = acc[rr] * adv;
#pragma unroll
    for (int off = 32; off > 0; off >>= 1) {
      vs += __shfl_xor(vs, off);
      vd += __shfl_xor(vd, off);
    }
    if (c == 0) { AS2[row] = vs; AD2[row] = vd; }
  }
}

// ---------------- GAT layer-2 aggregation, FUSED edge weights ----------------
__global__ __launch_bounds__(256) void k_agg2(
    const int* __restrict__ rp, const int* __restrict__ col,
    const float* __restrict__ AS2, const float* __restrict__ AD2,
    const float* __restrict__ h2, const float* __restrict__ b2,
    float* __restrict__ out) {
  int wave = threadIdx.x >> 6, lane = threadIdx.x & 63;
  int n = blockIdx.x * 4 + wave;
  int g = lane >> 4, c4 = (lane & 15) * 4;
  int e0 = rp[n], e1 = rp[n + 1];
  float adv = AD2[n];
  float ax = 0.f, ay = 0.f, az = 0.f, aw = 0.f, den = 0.f;
#pragma unroll 2
  for (int e = e0; e < e1; e += 4) {
    int ee = e + g;
    bool valid = ee < e1;
    int ec = valid ? ee : e1 - 1;
    int s = col[ec];
    float ev = AS2[s] + adv;
    ev = ev > 0.f ? ev : NEG * ev;
    float p = valid ? __expf(ev) : 0.f;
    float4 hv = *(const float4*)(h2 + (size_t)s * 64 + c4);
    ax += p * hv.x; ay += p * hv.y; az += p * hv.z; aw += p * hv.w;
    den += p;
  }
  ax += __shfl_xor(ax, 16); ax += __shfl_xor(ax, 32);
  ay += __shfl_xor(ay, 16); ay += __shfl_xor(ay, 32);
  az += __shfl_xor(az, 16); az += __shfl_xor(az, 32);
  aw += __shfl_xor(aw, 16); aw += __shfl_xor(aw, 32);
  den += __shfl_xor(den, 16); den += __shfl_xor(den, 32);
  if (lane < 16) {
    float inv = 1.f / den;
    float4 bv = *(const float4*)(b2 + c4);
    float4 o;
    o.x = ax * inv + bv.x; o.y = ay * inv + bv.y;
    o.z = az * inv + bv.z; o.w = aw * inv + bv.w;
    o.x = o.x > 0.f ? o.x : __expf(o.x) - 1.f;
    o.y = o.y > 0.f ? o.y : __expf(o.y) - 1.f;
    o.z = o.z > 0.f ? o.z : __expf(o.z) - 1.f;
    o.w = o.w > 0.f ? o.w : __expf(o.w) - 1.f;
    *(float4*)(out + (size_t)n * 64 + c4) = o;
  }
}

// ---------------- pair MLP v10: v6 structure + VGPR headroom + ck ping-pong prefetch ------
// Block = 128 threads = 2 waves, 64 pairs (200000 = 64*3125 exactly). Wave hu computes
// z-half hu (32 units) then output-column chunk hu (43 cols). Round-7 limiter was
// VGPR_Count=44 < 48 live (allocator's occupancy-greedy default) -> gathers dribbled.
// __launch_bounds__(128, 4) caps at 512/4 = 128 VGPRs: acc[32] + ckA[16] + ckB[16] ~ 72
// live fits with slack. ckA/ckB ping-pong: group g+1's four float4 gathers issue BEFORE
// group g's 512-FMA block -> L2 latency hidden inside the FMA stream.
// Weights stay thread-uniform (hu via readfirstlane) with consecutive compile-time inner
// index -> batched s_load_dwordx16 on the scalar pipe, dual-issued with v_fmac.
#define PB 128

__global__ __launch_bounds__(PB, 4) void k_pairs(
    const int* __restrict__ pairs, const float* __restrict__ h2a,
    const float* __restrict__ Wp1, const float* __restrict__ bp1,
    const float* __restrict__ Wp2, const float* __restrict__ bp2,
    float* __restrict__ out) {
  __shared__ float zt[64][66];  // [t][pair]
  int tid = threadIdx.x;
  int pp = tid & 63;                                      // pair within block
  int hu = __builtin_amdgcn_readfirstlane(tid >> 6);      // wave id 0/1, provably uniform
  int p = blockIdx.x * 64 + pp;
  int pi = pairs[2 * p], pj = pairs[2 * p + 1];
  const float* rowi = h2a + pi * 64;
  const float* rowj = h2a + pj * 64;

  // layer 1: z[hu*32+u] = relu(bp1 + sum_k comb[k]*Wp1[k][hu*32+u])
  {
    float acc[32];
#pragma unroll
    for (int u = 0; u < 32; ++u) acc[u] = bp1[hu * 32 + u];

    float ckA[16], ckB[16];
    // prologue: group 0 -> ckA
#pragma unroll
    for (int q = 0; q < 4; ++q) {
      float4 v = *(const float4*)(rowi + q * 4);
      ckA[q * 4] = v.x; ckA[q * 4 + 1] = v.y; ckA[q * 4 + 2] = v.z; ckA[q * 4 + 3] = v.w;
    }
#pragma unroll 1
    for (int gg = 0; gg < 4; ++gg) {
      int g0 = 2 * gg, g1 = 2 * gg + 1;
      // prefetch group g1 -> ckB (before g0's FMA block)
      {
        const float* src = (g1 < 4) ? rowi : rowj;
        int off = (g1 & 3) * 16;
#pragma unroll
        for (int q = 0; q < 4; ++q) {
          float4 v = *(const float4*)(src + off + q * 4);
          ckB[q * 4] = v.x; ckB[q * 4 + 1] = v.y; ckB[q * 4 + 2] = v.z; ckB[q * 4 + 3] = v.w;
        }
      }
      // FMA block for group g0 (ckA)
      {
        int k0 = g0 * 16;
#pragma unroll
        for (int kk = 0; kk < 16; ++kk)
#pragma unroll
          for (int u = 0; u < 32; ++u)
            acc[u] += ckA[kk] * Wp1[(k0 + kk) * 64 + hu * 32 + u];
      }
      // prefetch group g0+2 -> ckA (before g1's FMA block)
      if (gg < 3) {
        int g2 = g0 + 2;
        const float* src = (g2 < 4) ? rowi : rowj;
        int off = (g2 & 3) * 16;
#pragma unroll
        for (int q = 0; q < 4; ++q) {
          float4 v = *(const float4*)(src + off + q * 4);
          ckA[q * 4] = v.x; ckA[q * 4 + 1] = v.y; ckA[q * 4 + 2] = v.z; ckA[q * 4 + 3] = v.w;
        }
      }
      // FMA block for group g1 (ckB)
      {
        int k0 = g1 * 16;
#pragma unroll
        for (int kk = 0; kk < 16; ++kk)
#pragma unroll
          for (int u = 0; u < 32; ++u)
            acc[u] += ckB[kk] * Wp1[(k0 + kk) * 64 + hu * 32 + u];
      }
    }
#pragma unroll
    for (int u = 0; u < 32; ++u) zt[hu * 32 + u][pp] = fmaxf(acc[u], 0.f);
  }
  __syncthreads();

  // layer 2: out[p][hu*43 + j] = bp2 + sum_t z[t]*Wp2[t][hu*43+j], 43 cols per wave
  {
    float acc2[43];
#pragma unroll
    for (int j = 0; j < 43; ++j) acc2[j] = bp2[hu * 43 + j];
#pragma unroll 2
    for (int t = 0; t < 64; ++t) {
      float zv = zt[t][pp];
#pragma unroll
      for (int j = 0; j < 43; ++j)
        acc2[j] += zv * Wp2[t * 86 + hu * 43 + j];  // uniform, j-consecutive
    }
#pragma unroll
    for (int j = 0; j < 43; ++j) out[(size_t)p * 86 + hu * 43 + j] = acc2[j];
  }
}

extern "C" void kernel_launch(void* const* d_in, const int* in_sizes, int n_in,
                              void* d_out, int out_size, void* d_ws, size_t ws_size,
                              hipStream_t stream) {
  (void)in_sizes; (void)n_in; (void)out_size; (void)ws_size;
  const float* x      = (const float*)d_in[0];
  const int*   ei     = (const int*)d_in[1];
  const int*   pairs  = (const int*)d_in[2];
  const float* W1     = (const float*)d_in[3];
  const float* a_src1 = (const float*)d_in[4];
  const float* a_dst1 = (const float*)d_in[5];
  const float* b1     = (const float*)d_in[6];
  const float* W2     = (const float*)d_in[7];
  const float* a_src2 = (const float*)d_in[8];
  const float* a_dst2 = (const float*)d_in[9];
  const float* b2     = (const float*)d_in[10];
  const float* Wp1    = (const float*)d_in[11];
  const float* bp1    = (const float*)d_in[12];
  const float* Wp2    = (const float*)d_in[13];
  const float* bp2    = (const float*)d_in[14];
  float* out = (float*)d_out;

  char* w = (char*)d_ws;
  auto alloc = [&](size_t bytes) -> void* {
    void* pp = (void*)w;
    w += (bytes + 255) & ~(size_t)255;
    return pp;
  };
  float* h1    = (float*)alloc((size_t)NN * 256 * 4);  // head-major [4][NN][64]
  float* AS1   = (float*)alloc((size_t)NN * 4 * 4);
  float* AD1   = (float*)alloc((size_t)NN * 4 * 4);
  float* h1agg = (float*)alloc((size_t)NN * 256 * 4);
  float* h2    = (float*)alloc((size_t)NN * 64 * 4);
  float* AS2   = (float*)alloc((size_t)NN * 4);
  float* AD2   = (float*)alloc((size_t)NN * 4);
  float* h2agg = (float*)alloc((size_t)NN * 64 * 4);
  int*   rp    = (int*)alloc((size_t)(NN + 1) * 4);
  int*   cnt   = (int*)alloc((size_t)NN * 4);
  int*   cur   = (int*)alloc((size_t)NN * 4);
  int*   col   = (int*)alloc((size_t)NEE * 4);

  hipMemsetAsync(cnt, 0, (size_t)NN * 4, stream);
  hipMemsetAsync(cur, 0, (size_t)NN * 4, stream);

  const int EB = (NEE + 255) / 256;  // 2579
  k_hist<<<EB, 256, 0, stream>>>(ei, cnt);
  k_scan<<<1, 1024, 0, stream>>>(cnt, rp);
  k_scatter<<<EB, 256, 0, stream>>>(ei, rp, cur, col);

  k_gemm1<<<NN / 16, 256, 0, stream>>>(x, W1, a_src1, a_dst1, h1, AS1, AD1);
  k_agg1<<<dim3(NN / 4, 4), 256, 0, stream>>>(rp, col, AS1, AD1, h1, b1, h1agg);

  k_gemm2<<<NN / 16, 256, 0, stream>>>(h1agg, W2, a_src2, a_dst2, h2, AS2, AD2);
  k_agg2<<<NN / 4, 256, 0, stream>>>(rp, col, AS2, AD2, h2, b2, h2agg);

  k_pairs<<<NP / 64, PB, 0, stream>>>(pairs, h2agg, Wp1, bp1, Wp2, bp2, out);
}